// Round 9
// baseline (166.929 us; speedup 1.0000x reference)
//
#include <hip/hip_runtime.h>
#include <hip/hip_bf16.h>

// Sparse residual block: 2x (gather-GEMM-scatter conv 27x64x64 + BN + LeakyReLU) + residual.
// ABI: f32 in / f32 out. Internally bf16 MFMA (16x16x32) with f32 accumulation.
//
// R9 restructure vs R7/R8 (LDS-throughput-bound fix):
//  - A fragments gathered DIRECTLY global->VGPR per lane (no LDS staging, no
//    swizzle, no barriers in the k-loop). B fragments global->VGPR (L1-bcast).
//  - Per-wave ping-pong software pipeline (AE/BE, AO/BO named sets, unroll-2),
//    compiler-scheduled waits; in-order vmcnt leaves next tap's loads in flight.
//  - LDS = nbr indices + BN reduction only (~15.5 KB) -> 3 blocks/CU.

#define N_VOX 100000
#define NCH 64
#define NK 27
#define ROWS 128
#define NBLK ((N_VOX + ROWS - 1) / ROWS)   // 782

typedef __hip_bfloat16 bf16;
typedef __attribute__((ext_vector_type(8))) short bf16x8;   // 8 bf16 = 4 VGPR
typedef __attribute__((ext_vector_type(4))) float f32x4;

__device__ __forceinline__ float b2f(short s) {
  unsigned u = ((unsigned)(unsigned short)s) << 16;
  return __builtin_bit_cast(float, u);
}
__device__ __forceinline__ short f2b(float f) {
  __hip_bfloat16 h = __float2bfloat16(f);
  return __builtin_bit_cast(short, h);
}

// ---------------------------------------------------------------------------
// Cast feats f32 -> bf16, append zero sentinel row at index N.
__global__ void cast_feats(const float* __restrict__ feats, bf16* __restrict__ fbf) {
  const size_t i = ((size_t)blockIdx.x * 256 + threadIdx.x) * 8;
  if (i >= (size_t)(N_VOX + 1) * NCH) return;
  bf16x8 o;
  if (i < (size_t)N_VOX * NCH) {
    const f32x4 v0 = *reinterpret_cast<const f32x4*>(feats + i);
    const f32x4 v1 = *reinterpret_cast<const f32x4*>(feats + i + 4);
#pragma unroll
    for (int e = 0; e < 8; ++e) o[e] = f2b(e < 4 ? v0[e] : v1[e - 4]);
  } else {
#pragma unroll
    for (int e = 0; e < 8; ++e) o[e] = 0;
  }
  *reinterpret_cast<bf16x8*>((short*)fbf + i) = o;
}

// ---------------------------------------------------------------------------
// Pack W[k][c][o] (27,64,64 f32) into bf16 MFMA B-fragment order:
// frag id q = ((k*4 + j)*2 + kb)*64 + lane ; lane's 8 contiguous bf16:
//   B[kb*32 + (lane>>4)*8 + e][j*16 + (lane&15)]
__global__ void pack_w(const float* __restrict__ W1, const float* __restrict__ W2,
                       bf16* __restrict__ wp1, bf16* __restrict__ wp2) {
  const int t = blockIdx.x * 256 + threadIdx.x;
  const int half = NK * 4 * 2 * 64;  // 13824
  if (t >= 2 * half) return;
  const float* W = (t < half) ? W1 : W2;
  short* wp = (short*)((t < half) ? wp1 : wp2);
  const int q = (t < half) ? t : t - half;
  const int l  = q & 63;
  const int kb = (q >> 6) & 1;
  const int j  = (q >> 7) & 3;
  const int k  = q >> 9;
  const int oo = j * 16 + (l & 15);
  const int c0 = kb * 32 + (l >> 4) * 8;
  bf16x8 v;
#pragma unroll
  for (int e = 0; e < 8; ++e)
    v[e] = f2b(W[((size_t)k * 64 + c0 + e) * 64 + oo]);
  *reinterpret_cast<bf16x8*>(&wp[(size_t)q * 8]) = v;
}

// ---------------------------------------------------------------------------
// Gather-GEMM: y[n,o] = sum_k sum_c feat[nbr[k,n], c] * W[k,c,o]
// feat has N+1 rows (row N = zeros). 128 rows/block, 4 waves x 32 rows x 64 cols.
// Barrier-free k-loop: per-wave ping-pong prefetch, A gathered straight to
// VGPRs (per-lane 16B), B coalesced to VGPRs. LDS = nbr indices + BN only.
__global__ __launch_bounds__(256, 3)
void conv_mfma(const bf16* __restrict__ feat, const bf16* __restrict__ wp,
               const int* __restrict__ nbr, bf16* __restrict__ y,
               float* __restrict__ part) {
  __shared__ int nbrL[NK * ROWS];        // 13.5 KB neighbor indices
  __shared__ float redS[4][NCH];
  __shared__ float redQ[4][NCH];

  const int tid = threadIdx.x;
  const int lane = tid & 63;
  const int wv = tid >> 6;

  // XCD-chunked bijective swizzle (m204) for L2 gather locality.
  const int nwg = NBLK;                 // 782
  const int xcd = blockIdx.x & 7;
  const int pos = blockIdx.x >> 3;
  const int q8 = nwg >> 3, r8 = nwg & 7;
  const int bid = (xcd < r8 ? xcd * (q8 + 1) : r8 * (q8 + 1) + (xcd - r8) * q8) + pos;
  const int n0 = bid * ROWS;

  // Preload all 27*128 neighbor indices for this block (coalesced, 14 rounds).
  for (int t = tid; t < NK * ROWS; t += 256) {
    const int k = t >> 7;
    const int rr = t & (ROWS - 1);
    nbrL[t] = (n0 + rr < N_VOX) ? nbr[(size_t)k * N_VOX + n0 + rr] : N_VOX;
  }
  __syncthreads();

  const int r0 = wv * 32 + (lane & 15);  // row (h=0) this lane owns
  const int koff = (lane >> 4) * 8;      // k-element offset within a row

  f32x4 acc[2][4];
#pragma unroll
  for (int h = 0; h < 2; ++h)
#pragma unroll
    for (int j = 0; j < 4; ++j)
      acc[h][j] = (f32x4){0.f, 0.f, 0.f, 0.f};

  // A set: 4 frags = {h=0,1} x {kb=0,1}; per-lane gathered 16B loads.
  // B set: 8 frags, coalesced (all waves same addresses -> L1 broadcast).
  bf16x8 AE[4], AO[4], BE[8], BO[8];

#define LOAD_A(A, k)                                                        \
  {                                                                         \
    const int i0 = nbrL[(k) * ROWS + r0];                                   \
    const int i1 = nbrL[(k) * ROWS + r0 + 16];                              \
    A[0] = *reinterpret_cast<const bf16x8*>(feat + (size_t)i0 * 64 + koff); \
    A[1] = *reinterpret_cast<const bf16x8*>(feat + (size_t)i0 * 64 + 32 + koff); \
    A[2] = *reinterpret_cast<const bf16x8*>(feat + (size_t)i1 * 64 + koff); \
    A[3] = *reinterpret_cast<const bf16x8*>(feat + (size_t)i1 * 64 + 32 + koff); \
  }

#define LOAD_B(B, k)                                                        \
  {                                                                         \
    const short* wpk = (const short*)wp + (size_t)(k) * 4096 + lane * 8;    \
    _Pragma("unroll")                                                       \
    for (int f = 0; f < 8; ++f)                                             \
      B[f] = *reinterpret_cast<const bf16x8*>(wpk + f * 512);               \
  }

#define MFMA_TAP(A, B)                                                      \
  _Pragma("unroll")                                                         \
  for (int h = 0; h < 2; ++h)                                               \
    _Pragma("unroll")                                                       \
    for (int j = 0; j < 4; ++j)                                             \
      _Pragma("unroll")                                                     \
      for (int kb = 0; kb < 2; ++kb)                                        \
        acc[h][j] = __builtin_amdgcn_mfma_f32_16x16x32_bf16(                \
            A[h * 2 + kb], B[j * 2 + kb], acc[h][j], 0, 0, 0);

  // Prologue: tap 0 in flight.
  LOAD_B(BE, 0)
  LOAD_A(AE, 0)

#pragma unroll 1
  for (int j = 0; j < 13; ++j) {
    const int t = 2 * j;
    LOAD_B(BO, t + 1)      // prefetch tap t+1 (stays in flight past mfma(t))
    LOAD_A(AO, t + 1)
    MFMA_TAP(AE, BE)       // waits only pair(t); pair(t+1) remains outstanding
    LOAD_B(BE, t + 2)      // prefetch tap t+2
    LOAD_A(AE, t + 2)
    MFMA_TAP(AO, BO)
  }
  MFMA_TAP(AE, BE)         // tap 26

#undef LOAD_A
#undef LOAD_B
#undef MFMA_TAP

  // Store y (bf16). D layout: col = lane&15, row = (lane>>4)*4 + r  [m89]
#pragma unroll
  for (int h = 0; h < 2; ++h)
#pragma unroll
    for (int j = 0; j < 4; ++j) {
      const int col = j * 16 + (lane & 15);
#pragma unroll
      for (int r = 0; r < 4; ++r) {
        const int row = n0 + wv * 32 + h * 16 + (lane >> 4) * 4 + r;
        if (row < N_VOX) ((short*)y)[(size_t)row * NCH + col] = f2b(acc[h][j][r]);
      }
    }

  // BN partial sums: per-channel sum and sum-of-squares over this block's rows
  // (zero-padded tail rows contribute 0).
#pragma unroll
  for (int j = 0; j < 4; ++j) {
    float s1 = 0.f, s2 = 0.f;
#pragma unroll
    for (int h = 0; h < 2; ++h)
#pragma unroll
      for (int r = 0; r < 4; ++r) {
        const float v = acc[h][j][r];
        s1 += v;
        s2 += v * v;
      }
    s1 += __shfl_xor(s1, 16); s2 += __shfl_xor(s2, 16);
    s1 += __shfl_xor(s1, 32); s2 += __shfl_xor(s2, 32);
    if (lane < 16) {
      redS[wv][j * 16 + lane] = s1;
      redQ[wv][j * 16 + lane] = s2;
    }
  }
  __syncthreads();
  if (tid < NCH) {
    const float s1 = redS[0][tid] + redS[1][tid] + redS[2][tid] + redS[3][tid];
    const float s2 = redQ[0][tid] + redQ[1][tid] + redQ[2][tid] + redQ[3][tid];
    part[(size_t)blockIdx.x * 128 + tid] = s1;
    part[(size_t)blockIdx.x * 128 + 64 + tid] = s2;
  }
}

// ---------------------------------------------------------------------------
// Reduce per-block partials -> per-channel (a, shift): a = g*rsqrt(var+eps),
// shift = b - mean*a.  Grid: 64 blocks (one per channel) x 256 threads.
__global__ void finalize(const float* __restrict__ part, int nblk,
                         const float* __restrict__ g, const float* __restrict__ b,
                         float* __restrict__ ab) {
  __shared__ float r1[256], r2[256];
  const int c = blockIdx.x;
  const int t = threadIdx.x;
  float s1 = 0.f, s2 = 0.f;
  for (int bb = t; bb < nblk; bb += 256) {
    s1 += part[(size_t)bb * 128 + c];
    s2 += part[(size_t)bb * 128 + 64 + c];
  }
  r1[t] = s1; r2[t] = s2;
  __syncthreads();
  for (int off = 128; off > 0; off >>= 1) {
    if (t < off) { r1[t] += r1[t + off]; r2[t] += r2[t + off]; }
    __syncthreads();
  }
  if (t == 0) {
    const float m = r1[0] / (float)N_VOX;
    const float v = r2[0] / (float)N_VOX - m * m;
    const float a = g[c] * rsqrtf(v + 1e-5f);
    const float sh = b[c] - m * a;
    ab[c] = a;
    ab[64 + c] = sh;
  }
}

// ---------------------------------------------------------------------------
// z[n,c] = lrelu(y[n,c]*a[c]+s[c]) as bf16; row N (sentinel) = 0.
__global__ void bn_act(const bf16* __restrict__ y, const float* __restrict__ ab,
                       bf16* __restrict__ z) {
  const size_t i = ((size_t)blockIdx.x * 256 + threadIdx.x) * 8;
  if (i >= (size_t)(N_VOX + 1) * NCH) return;
  const int col = (int)(i & 63);
  bf16x8 o;
  if (i < (size_t)N_VOX * NCH) {
    const bf16x8 v = *reinterpret_cast<const bf16x8*>((const short*)y + i);
#pragma unroll
    for (int e = 0; e < 8; ++e) {
      float x = b2f(v[e]) * ab[col + e] + ab[64 + col + e];
      x = x < 0.f ? 0.01f * x : x;
      o[e] = f2b(x);
    }
  } else {
#pragma unroll
    for (int e = 0; e < 8; ++e) o[e] = 0;
  }
  *reinterpret_cast<bf16x8*>((short*)z + i) = o;
}

// ---------------------------------------------------------------------------
// out[n,c] = lrelu( feats[n,c] + lrelu(y[n,c]*a[c]+s[c]) ) as f32.
// Grid exact: N*C/2048 = 3125 blocks, no tail.
__global__ void bn_act_res(const bf16* __restrict__ y, const float* __restrict__ ab,
                           const float* __restrict__ feats, float* __restrict__ out) {
  const size_t i = ((size_t)blockIdx.x * 256 + threadIdx.x) * 8;
  const int col = (int)(i & 63);
  const bf16x8 v = *reinterpret_cast<const bf16x8*>((const short*)y + i);
  const f32x4 s0 = *reinterpret_cast<const f32x4*>(feats + i);
  const f32x4 s1 = *reinterpret_cast<const f32x4*>(feats + i + 4);
  f32x4 o0, o1;
#pragma unroll
  for (int e = 0; e < 8; ++e) {
    float x = b2f(v[e]) * ab[col + e] + ab[64 + col + e];
    x = x < 0.f ? 0.01f * x : x;                    // lrelu(bn2)
    float r = (e < 4 ? s0[e] : s1[e - 4]) + x;      // + skip
    r = r < 0.f ? 0.01f * r : r;                    // final lrelu
    if (e < 4) o0[e] = r; else o1[e - 4] = r;
  }
  *reinterpret_cast<f32x4*>(out + i) = o0;
  *reinterpret_cast<f32x4*>(out + i + 4) = o1;
}

// ---------------------------------------------------------------------------
extern "C" void kernel_launch(void* const* d_in, const int* in_sizes, int n_in,
                              void* d_out, int out_size, void* d_ws, size_t ws_size,
                              hipStream_t stream) {
  const float* feats = (const float*)d_in[0];
  const float* W1 = (const float*)d_in[1];
  const float* g1 = (const float*)d_in[2];
  const float* b1 = (const float*)d_in[3];
  const float* W2 = (const float*)d_in[4];
  const float* g2 = (const float*)d_in[5];
  const float* b2 = (const float*)d_in[6];
  const int* nbr = (const int*)d_in[7];
  float* out = (float*)d_out;

  char* p = (char*)d_ws;
  bf16* fbf = (bf16*)p; p += (size_t)(N_VOX + 1) * NCH * 2;   // 12.80 MB
  bf16* ybf = (bf16*)p; p += (size_t)N_VOX * NCH * 2;         // 12.80 MB
  bf16* z = (bf16*)p;   p += (size_t)(N_VOX + 1) * NCH * 2;   // 12.80 MB
  bf16* wp1 = (bf16*)p; p += 442368;
  bf16* wp2 = (bf16*)p; p += 442368;
  float* part = (float*)p; p += (size_t)NBLK * 128 * 4;       // 400 KB
  float* ab1 = (float*)p; p += 512;
  float* ab2 = (float*)p; p += 512;

  const int cast_blocks = (int)(((size_t)(N_VOX + 1) * NCH / 8 + 255) / 256);  // 3126

  cast_feats<<<cast_blocks, 256, 0, stream>>>(feats, fbf);
  pack_w<<<108, 256, 0, stream>>>(W1, W2, wp1, wp2);

  conv_mfma<<<NBLK, 256, 0, stream>>>(fbf, wp1, nbr, ybf, part);
  finalize<<<64, 256, 0, stream>>>(part, NBLK, g1, b1, ab1);
  bn_act<<<cast_blocks, 256, 0, stream>>>(ybf, ab1, z);

  conv_mfma<<<NBLK, 256, 0, stream>>>(z, wp2, nbr, ybf, part);
  finalize<<<64, 256, 0, stream>>>(part, NBLK, g2, b2, ab2);
  bn_act_res<<<(N_VOX * NCH / 8) / 256, 256, 0, stream>>>(ybf, ab2, feats, out);
}

// Round 10
// 134.725 us; speedup vs baseline: 1.2390x; 1.2390x over previous
//
#include <hip/hip_runtime.h>
#include <hip/hip_bf16.h>

// Sparse residual block: 2x (gather-GEMM-scatter conv 27x64x64 + BN + LeakyReLU) + residual.
// ABI: f32 in / f32 out. Internally bf16 MFMA (16x16x32) with f32 accumulation.
//
// R10 structure (synthesis of R7/R8/R9 evidence):
//  - A fragments: global->VGPR per-lane gather, ping-pong AE/AO, issue PINNED
//    with sched_barrier(0) (R9 failed because the backend sank unpinned loads).
//  - B fragments: LDS ring-3, staged once per block per tile (2 gload_lds/wave),
//    read as 8 ds_read_b128/wave — the only LDS reads left (R7 was LDS-bound).
//  - Ring-3 allows ONE s_barrier per tile (stage target (t+2)%3 never collides
//    with the slot read in the same barrier epoch).
//  - vmcnt: per tile issues A(t+1) [4] then Bstage(t+2) [2]; steady wait
//    vmcnt(2) => A aged 1 tile, Bstage aged 2 tiles. No drain in loop.
//  - LDS 40.4 KB -> 4 blocks/CU (16 waves/CU).

#define N_VOX 100000
#define NCH 64
#define NK 27
#define ROWS 128
#define NBLK ((N_VOX + ROWS - 1) / ROWS)   // 782

typedef __hip_bfloat16 bf16;
typedef __attribute__((ext_vector_type(8))) short bf16x8;   // 8 bf16 = 4 VGPR
typedef __attribute__((ext_vector_type(4))) float f32x4;

__device__ __forceinline__ float b2f(short s) {
  unsigned u = ((unsigned)(unsigned short)s) << 16;
  return __builtin_bit_cast(float, u);
}
__device__ __forceinline__ short f2b(float f) {
  __hip_bfloat16 h = __float2bfloat16(f);
  return __builtin_bit_cast(short, h);
}

__device__ __forceinline__ void gload16(const void* g, void* l) {
  __builtin_amdgcn_global_load_lds(
      (const __attribute__((address_space(1))) void*)g,
      (__attribute__((address_space(3))) void*)l, 16, 0, 0);
}

// ---------------------------------------------------------------------------
// Cast feats f32 -> bf16, append zero sentinel row at index N.
__global__ void cast_feats(const float* __restrict__ feats, bf16* __restrict__ fbf) {
  const size_t i = ((size_t)blockIdx.x * 256 + threadIdx.x) * 8;
  if (i >= (size_t)(N_VOX + 1) * NCH) return;
  bf16x8 o;
  if (i < (size_t)N_VOX * NCH) {
    const f32x4 v0 = *reinterpret_cast<const f32x4*>(feats + i);
    const f32x4 v1 = *reinterpret_cast<const f32x4*>(feats + i + 4);
#pragma unroll
    for (int e = 0; e < 8; ++e) o[e] = f2b(e < 4 ? v0[e] : v1[e - 4]);
  } else {
#pragma unroll
    for (int e = 0; e < 8; ++e) o[e] = 0;
  }
  *reinterpret_cast<bf16x8*>((short*)fbf + i) = o;
}

// ---------------------------------------------------------------------------
// Pack W[k][c][o] (27,64,64 f32) into bf16 MFMA B-fragment order:
// frag id q = ((k*4 + j)*2 + kb)*64 + lane ; lane's 8 contiguous bf16:
//   B[kb*32 + (lane>>4)*8 + e][j*16 + (lane&15)]
__global__ void pack_w(const float* __restrict__ W1, const float* __restrict__ W2,
                       bf16* __restrict__ wp1, bf16* __restrict__ wp2) {
  const int t = blockIdx.x * 256 + threadIdx.x;
  const int half = NK * 4 * 2 * 64;  // 13824
  if (t >= 2 * half) return;
  const float* W = (t < half) ? W1 : W2;
  short* wp = (short*)((t < half) ? wp1 : wp2);
  const int q = (t < half) ? t : t - half;
  const int l  = q & 63;
  const int kb = (q >> 6) & 1;
  const int j  = (q >> 7) & 3;
  const int k  = q >> 9;
  const int oo = j * 16 + (l & 15);
  const int c0 = kb * 32 + (l >> 4) * 8;
  bf16x8 v;
#pragma unroll
  for (int e = 0; e < 8; ++e)
    v[e] = f2b(W[((size_t)k * 64 + c0 + e) * 64 + oo]);
  *reinterpret_cast<bf16x8*>(&wp[(size_t)q * 8]) = v;
}

// ---------------------------------------------------------------------------
// Gather-GEMM: y[n,o] = sum_k sum_c feat[nbr[k,n], c] * W[k,c,o]
// feat has N+1 rows (row N = zeros). 128 rows/block, 4 waves x 32 rows x 64 cols.
__global__ __launch_bounds__(256, 4)
void conv_mfma(const bf16* __restrict__ feat, const bf16* __restrict__ wp,
               const int* __restrict__ nbr, bf16* __restrict__ y,
               float* __restrict__ part) {
  __shared__ short GB[3][8 * 512];       // 3 x 8 KB B-fragment ring
  __shared__ int nbrL[NK * ROWS];        // 13.5 KB neighbor indices
  __shared__ float redS[4][NCH];
  __shared__ float redQ[4][NCH];

  const int tid = threadIdx.x;
  const int lane = tid & 63;
  const int wv = tid >> 6;

  // XCD-chunked bijective swizzle (m204) for L2 gather locality.
  const int nwg = NBLK;                 // 782
  const int xcd = blockIdx.x & 7;
  const int pos = blockIdx.x >> 3;
  const int q8 = nwg >> 3, r8 = nwg & 7;
  const int bid = (xcd < r8 ? xcd * (q8 + 1) : r8 * (q8 + 1) + (xcd - r8) * q8) + pos;
  const int n0 = bid * ROWS;

  // Preload all 27*128 neighbor indices for this block (coalesced, 14 rounds).
  for (int t = tid; t < NK * ROWS; t += 256) {
    const int k = t >> 7;
    const int rr = t & (ROWS - 1);
    nbrL[t] = (n0 + rr < N_VOX) ? nbr[(size_t)k * N_VOX + n0 + rr] : N_VOX;
  }
  __syncthreads();   // drains preload vmem before the pipeline starts

  const int r0 = wv * 32 + (lane & 15);  // row (h=0) this lane owns
  const int koff = (lane >> 4) * 8;      // k-element offset within a row

  f32x4 acc[2][4];
#pragma unroll
  for (int h = 0; h < 2; ++h)
#pragma unroll
    for (int j = 0; j < 4; ++j)
      acc[h][j] = (f32x4){0.f, 0.f, 0.f, 0.f};

  bf16x8 AE[4], AO[4];

  // A frags {h}x{kb}: per-lane gathered 16B loads (layout verified R9, absmax ok).
#define LOAD_A(A, k)                                                        \
  {                                                                         \
    const int i0 = nbrL[(k) * ROWS + r0];                                   \
    const int i1 = nbrL[(k) * ROWS + r0 + 16];                              \
    A[0] = *reinterpret_cast<const bf16x8*>(feat + (size_t)i0 * 64 + koff); \
    A[1] = *reinterpret_cast<const bf16x8*>(feat + (size_t)i0 * 64 + 32 + koff); \
    A[2] = *reinterpret_cast<const bf16x8*>(feat + (size_t)i1 * 64 + koff); \
    A[3] = *reinterpret_cast<const bf16x8*>(feat + (size_t)i1 * 64 + 32 + koff); \
  }

  // Stage B tile k into ring slot: 2 gload_lds per wave (dest uniform, m104).
#define STAGE_B(slot, k)                                                    \
  {                                                                         \
    const short* srcb = (const short*)wp + (size_t)(k) * 4096 +             \
                        (wv * 2) * 512 + lane * 8;                          \
    gload16((const void*)srcb, (void*)&GB[slot][(wv * 2) * 512]);           \
    gload16((const void*)(srcb + 512), (void*)&GB[slot][(wv * 2 + 1) * 512]); \
  }

#define MFMA_TAP(A, B)                                                      \
  _Pragma("unroll")                                                         \
  for (int h = 0; h < 2; ++h)                                               \
    _Pragma("unroll")                                                       \
    for (int j = 0; j < 4; ++j)                                             \
      _Pragma("unroll")                                                     \
      for (int kb = 0; kb < 2; ++kb)                                        \
        acc[h][j] = __builtin_amdgcn_mfma_f32_16x16x32_bf16(                \
            A[h * 2 + kb], B[j * 2 + kb], acc[h][j], 0, 0, 0);

  // One tile. Issue order: A(t+1) [4 loads] then Bstage(t+2) [2] -> steady
  // wait vmcnt(2) covers A(t) and Bstage(t) with >=1 tile of aging.
#define TILE_STEP(Acur, Aoth, t, cur)                                       \
  {                                                                         \
    asm volatile("s_waitcnt vmcnt(2)" ::: "memory");                        \
    __builtin_amdgcn_sched_barrier(0);                                      \
    __builtin_amdgcn_s_barrier();                                           \
    LOAD_A(Aoth, (t) + 1)                                                   \
    if ((t) <= NK - 3) {                                                    \
      const int stslot = (cur) >= 1 ? (cur) - 1 : 2; /* (t+2)%3 */          \
      STAGE_B(stslot, (t) + 2)                                              \
    }                                                                       \
    __builtin_amdgcn_sched_barrier(0); /* pin loads above the MFMAs */      \
    bf16x8 Bf[8];                                                           \
    _Pragma("unroll")                                                       \
    for (int f = 0; f < 8; ++f)                                             \
      Bf[f] = *reinterpret_cast<const bf16x8*>(&GB[cur][f * 512 + lane * 8]); \
    MFMA_TAP(Acur, Bf)                                                      \
  }

  // Prologue: queue = [B0:2][A0:4][B1:2]; tile 0's vmcnt(2) drains B0+A0.
  STAGE_B(0, 0)
  LOAD_A(AE, 0)
  STAGE_B(1, 1)

  int cur = 0;
#pragma unroll 1
  for (int j = 0; j < 13; ++j) {
    const int t = 2 * j;
    TILE_STEP(AE, AO, t, cur)
    cur = (cur == 2) ? 0 : cur + 1;
    TILE_STEP(AO, AE, t + 1, cur)
    cur = (cur == 2) ? 0 : cur + 1;
  }
  // Epilogue: tile 26 (even -> AE), slot 26%3 == 2, nothing left to prefetch.
  {
    asm volatile("s_waitcnt vmcnt(0)" ::: "memory");
    __builtin_amdgcn_sched_barrier(0);
    __builtin_amdgcn_s_barrier();
    bf16x8 Bf[8];
#pragma unroll
    for (int f = 0; f < 8; ++f)
      Bf[f] = *reinterpret_cast<const bf16x8*>(&GB[2][f * 512 + lane * 8]);
    MFMA_TAP(AE, Bf)
  }

#undef LOAD_A
#undef STAGE_B
#undef MFMA_TAP
#undef TILE_STEP

  // Store y (bf16). D layout: col = lane&15, row = (lane>>4)*4 + r  [m89]
#pragma unroll
  for (int h = 0; h < 2; ++h)
#pragma unroll
    for (int j = 0; j < 4; ++j) {
      const int col = j * 16 + (lane & 15);
#pragma unroll
      for (int r = 0; r < 4; ++r) {
        const int row = n0 + wv * 32 + h * 16 + (lane >> 4) * 4 + r;
        if (row < N_VOX) ((short*)y)[(size_t)row * NCH + col] = f2b(acc[h][j][r]);
      }
    }

  // BN partial sums: per-channel sum and sum-of-squares over this block's rows
  // (zero-padded tail rows contribute 0).
#pragma unroll
  for (int j = 0; j < 4; ++j) {
    float s1 = 0.f, s2 = 0.f;
#pragma unroll
    for (int h = 0; h < 2; ++h)
#pragma unroll
      for (int r = 0; r < 4; ++r) {
        const float v = acc[h][j][r];
        s1 += v;
        s2 += v * v;
      }
    s1 += __shfl_xor(s1, 16); s2 += __shfl_xor(s2, 16);
    s1 += __shfl_xor(s1, 32); s2 += __shfl_xor(s2, 32);
    if (lane < 16) {
      redS[wv][j * 16 + lane] = s1;
      redQ[wv][j * 16 + lane] = s2;
    }
  }
  __syncthreads();
  if (tid < NCH) {
    const float s1 = redS[0][tid] + redS[1][tid] + redS[2][tid] + redS[3][tid];
    const float s2 = redQ[0][tid] + redQ[1][tid] + redQ[2][tid] + redQ[3][tid];
    part[(size_t)blockIdx.x * 128 + tid] = s1;
    part[(size_t)blockIdx.x * 128 + 64 + tid] = s2;
  }
}

// ---------------------------------------------------------------------------
// Reduce per-block partials -> per-channel (a, shift): a = g*rsqrt(var+eps),
// shift = b - mean*a.  Grid: 64 blocks (one per channel) x 256 threads.
__global__ void finalize(const float* __restrict__ part, int nblk,
                         const float* __restrict__ g, const float* __restrict__ b,
                         float* __restrict__ ab) {
  __shared__ float r1[256], r2[256];
  const int c = blockIdx.x;
  const int t = threadIdx.x;
  float s1 = 0.f, s2 = 0.f;
  for (int bb = t; bb < nblk; bb += 256) {
    s1 += part[(size_t)bb * 128 + c];
    s2 += part[(size_t)bb * 128 + 64 + c];
  }
  r1[t] = s1; r2[t] = s2;
  __syncthreads();
  for (int off = 128; off > 0; off >>= 1) {
    if (t < off) { r1[t] += r1[t + off]; r2[t] += r2[t + off]; }
    __syncthreads();
  }
  if (t == 0) {
    const float m = r1[0] / (float)N_VOX;
    const float v = r2[0] / (float)N_VOX - m * m;
    const float a = g[c] * rsqrtf(v + 1e-5f);
    const float sh = b[c] - m * a;
    ab[c] = a;
    ab[64 + c] = sh;
  }
}

// ---------------------------------------------------------------------------
// z[n,c] = lrelu(y[n,c]*a[c]+s[c]) as bf16; row N (sentinel) = 0.
__global__ void bn_act(const bf16* __restrict__ y, const float* __restrict__ ab,
                       bf16* __restrict__ z) {
  const size_t i = ((size_t)blockIdx.x * 256 + threadIdx.x) * 8;
  if (i >= (size_t)(N_VOX + 1) * NCH) return;
  const int col = (int)(i & 63);
  bf16x8 o;
  if (i < (size_t)N_VOX * NCH) {
    const bf16x8 v = *reinterpret_cast<const bf16x8*>((const short*)y + i);
#pragma unroll
    for (int e = 0; e < 8; ++e) {
      float x = b2f(v[e]) * ab[col + e] + ab[64 + col + e];
      x = x < 0.f ? 0.01f * x : x;
      o[e] = f2b(x);
    }
  } else {
#pragma unroll
    for (int e = 0; e < 8; ++e) o[e] = 0;
  }
  *reinterpret_cast<bf16x8*>((short*)z + i) = o;
}

// ---------------------------------------------------------------------------
// out[n,c] = lrelu( feats[n,c] + lrelu(y[n,c]*a[c]+s[c]) ) as f32.
// Grid exact: N*C/2048 = 3125 blocks, no tail.
__global__ void bn_act_res(const bf16* __restrict__ y, const float* __restrict__ ab,
                           const float* __restrict__ feats, float* __restrict__ out) {
  const size_t i = ((size_t)blockIdx.x * 256 + threadIdx.x) * 8;
  const int col = (int)(i & 63);
  const bf16x8 v = *reinterpret_cast<const bf16x8*>((const short*)y + i);
  const f32x4 s0 = *reinterpret_cast<const f32x4*>(feats + i);
  const f32x4 s1 = *reinterpret_cast<const f32x4*>(feats + i + 4);
  f32x4 o0, o1;
#pragma unroll
  for (int e = 0; e < 8; ++e) {
    float x = b2f(v[e]) * ab[col + e] + ab[64 + col + e];
    x = x < 0.f ? 0.01f * x : x;                    // lrelu(bn2)
    float r = (e < 4 ? s0[e] : s1[e - 4]) + x;      // + skip
    r = r < 0.f ? 0.01f * r : r;                    // final lrelu
    if (e < 4) o0[e] = r; else o1[e - 4] = r;
  }
  *reinterpret_cast<f32x4*>(out + i) = o0;
  *reinterpret_cast<f32x4*>(out + i + 4) = o1;
}

// ---------------------------------------------------------------------------
extern "C" void kernel_launch(void* const* d_in, const int* in_sizes, int n_in,
                              void* d_out, int out_size, void* d_ws, size_t ws_size,
                              hipStream_t stream) {
  const float* feats = (const float*)d_in[0];
  const float* W1 = (const float*)d_in[1];
  const float* g1 = (const float*)d_in[2];
  const float* b1 = (const float*)d_in[3];
  const float* W2 = (const float*)d_in[4];
  const float* g2 = (const float*)d_in[5];
  const float* b2 = (const float*)d_in[6];
  const int* nbr = (const int*)d_in[7];
  float* out = (float*)d_out;

  char* p = (char*)d_ws;
  bf16* fbf = (bf16*)p; p += (size_t)(N_VOX + 1) * NCH * 2;   // 12.80 MB
  bf16* ybf = (bf16*)p; p += (size_t)N_VOX * NCH * 2;         // 12.80 MB
  bf16* z = (bf16*)p;   p += (size_t)(N_VOX + 1) * NCH * 2;   // 12.80 MB
  bf16* wp1 = (bf16*)p; p += 442368;
  bf16* wp2 = (bf16*)p; p += 442368;
  float* part = (float*)p; p += (size_t)NBLK * 128 * 4;       // 400 KB
  float* ab1 = (float*)p; p += 512;
  float* ab2 = (float*)p; p += 512;

  const int cast_blocks = (int)(((size_t)(N_VOX + 1) * NCH / 8 + 255) / 256);  // 3126

  cast_feats<<<cast_blocks, 256, 0, stream>>>(feats, fbf);
  pack_w<<<108, 256, 0, stream>>>(W1, W2, wp1, wp2);

  conv_mfma<<<NBLK, 256, 0, stream>>>(fbf, wp1, nbr, ybf, part);
  finalize<<<64, 256, 0, stream>>>(part, NBLK, g1, b1, ab1);
  bn_act<<<cast_blocks, 256, 0, stream>>>(ybf, ab1, z);

  conv_mfma<<<NBLK, 256, 0, stream>>>(z, wp2, nbr, ybf, part);
  finalize<<<64, 256, 0, stream>>>(part, NBLK, g2, b2, ab2);
  bn_act_res<<<(N_VOX * NCH / 8) / 256, 256, 0, stream>>>(ybf, ab2, feats, out);
}